// Round 1
// baseline (106.436 us; speedup 1.0000x reference)
//
#include <hip/hip_runtime.h>

// Problem constants (fixed by setup_inputs): B=4, M=2048, C=4, V=4.
#define B_DIM 4
#define M_DIM 2048
#define M_SHIFT 11          // log2(M_DIM)
#define NPOS (1LL * B_DIM * M_DIM * M_DIM)   // 16,777,216 float4 positions
#define NBLOCKS 2048
#define NTHREADS 256

// Pass 1: grid-stride streaming reduction.
// Each position (b,i,j) is one float4 (channels c0,c1 = "t", c2,c3 = "s").
// Accumulate: all_t, all_s, intra_t, intra_s. Per-block partials -> d_ws.
__global__ __launch_bounds__(NTHREADS) void pose_loss_reduce(
    const float4* __restrict__ pred, const float4* __restrict__ gt,
    const int* __restrict__ Ms, float* __restrict__ partials)
{
    // Segment boundaries from Ms (V=4): seg(i) = (i>=c1)+(i>=c2)+(i>=c3)
    const int c1 = Ms[0];
    const int c2 = c1 + Ms[1];
    const int c3 = c2 + Ms[2];

    float at = 0.f, as_ = 0.f, it = 0.f, is_ = 0.f;
    const long long stride = (long long)gridDim.x * blockDim.x;
    for (long long idx = (long long)blockIdx.x * blockDim.x + threadIdx.x;
         idx < NPOS; idx += stride) {
        float4 p = pred[idx];
        float4 g = gt[idx];
        float d0 = p.x - g.x, d1 = p.y - g.y;
        float d2 = p.z - g.z, d3 = p.w - g.w;
        float et = d0 * d0 + d1 * d1;
        float es = d2 * d2 + d3 * d3;
        at  += et;
        as_ += es;
        int j = (int)(idx & (M_DIM - 1));
        int i = (int)((idx >> M_SHIFT) & (M_DIM - 1));
        int si = (i >= c1) + (i >= c2) + (i >= c3);
        int sj = (j >= c1) + (j >= c2) + (j >= c3);
        if (si == sj) { it += et; is_ += es; }
    }

    // Wave (64-lane) butterfly reduce
    for (int off = 32; off > 0; off >>= 1) {
        at  += __shfl_down(at,  off);
        as_ += __shfl_down(as_, off);
        it  += __shfl_down(it,  off);
        is_ += __shfl_down(is_, off);
    }

    __shared__ float smem[4][4];          // 4 waves x 4 sums
    const int wave = threadIdx.x >> 6;
    const int lane = threadIdx.x & 63;
    if (lane == 0) {
        smem[wave][0] = at;  smem[wave][1] = as_;
        smem[wave][2] = it;  smem[wave][3] = is_;
    }
    __syncthreads();
    if (threadIdx.x == 0) {
        float a0 = 0.f, a1 = 0.f, a2 = 0.f, a3 = 0.f;
        for (int w = 0; w < 4; ++w) {
            a0 += smem[w][0]; a1 += smem[w][1];
            a2 += smem[w][2]; a3 += smem[w][3];
        }
        float* o = partials + (size_t)blockIdx.x * 4;
        o[0] = a0; o[1] = a1; o[2] = a2; o[3] = a3;
    }
}

// Pass 2: single-block deterministic reduction of partials + finalize math.
__global__ __launch_bounds__(NTHREADS) void pose_loss_finalize(
    const float* __restrict__ partials, const int* __restrict__ Ms,
    float* __restrict__ out, int nblocks)
{
    float a0 = 0.f, a1 = 0.f, a2 = 0.f, a3 = 0.f;
    for (int b = threadIdx.x; b < nblocks; b += blockDim.x) {
        const float* p = partials + (size_t)b * 4;
        a0 += p[0]; a1 += p[1]; a2 += p[2]; a3 += p[3];
    }
    for (int off = 32; off > 0; off >>= 1) {
        a0 += __shfl_down(a0, off);
        a1 += __shfl_down(a1, off);
        a2 += __shfl_down(a2, off);
        a3 += __shfl_down(a3, off);
    }
    __shared__ float smem[4][4];
    const int wave = threadIdx.x >> 6;
    const int lane = threadIdx.x & 63;
    if (lane == 0) {
        smem[wave][0] = a0; smem[wave][1] = a1;
        smem[wave][2] = a2; smem[wave][3] = a3;
    }
    __syncthreads();
    if (threadIdx.x == 0) {
        float all_t = 0.f, all_s = 0.f, intra_t = 0.f, intra_s = 0.f;
        for (int w = 0; w < 4; ++w) {
            all_t   += smem[w][0];
            all_s   += smem[w][1];
            intra_t += smem[w][2];
            intra_s += smem[w][3];
        }
        long long ssq = 0;
        for (int v = 0; v < 4; ++v) {
            long long m = (long long)Ms[v];
            ssq += m * m;
        }
        const float diag = (float)(ssq * (long long)B_DIM);
        const float offd = (float)(((long long)M_DIM * M_DIM - ssq) * (long long)B_DIM);

        const float inter_t = all_t - intra_t;
        const float inter_s = all_s - intra_s;

        const float li_t = (diag > 1e-8f) ? intra_t / diag : 0.f;
        const float le_t = (offd > 1e-8f) ? inter_t / offd : 0.f;
        const float li_s = (diag > 1e-8f) ? intra_s / diag : 0.f;
        const float le_s = (offd > 1e-8f) ? inter_s / offd : 0.f;

        // ALPHA_T=0.5, ALPHA_S=0.75, ALPHA_TS=0.5
        const float lt = 0.5f * le_t + 0.5f * li_t;
        const float ls = 0.75f * le_s + 0.25f * li_s;
        const float loss = 0.5f * lt + 0.5f * ls;

        out[0] = li_t; out[1] = le_t; out[2] = li_s; out[3] = le_s;
        out[4] = lt;   out[5] = ls;   out[6] = loss;
    }
}

extern "C" void kernel_launch(void* const* d_in, const int* in_sizes, int n_in,
                              void* d_out, int out_size, void* d_ws, size_t ws_size,
                              hipStream_t stream) {
    const float4* pred = (const float4*)d_in[0];
    const float4* gt   = (const float4*)d_in[1];
    const int*    Ms   = (const int*)d_in[2];
    float* out      = (float*)d_out;
    float* partials = (float*)d_ws;   // NBLOCKS*4 floats = 32 KB

    pose_loss_reduce<<<NBLOCKS, NTHREADS, 0, stream>>>(pred, gt, Ms, partials);
    pose_loss_finalize<<<1, NTHREADS, 0, stream>>>(partials, Ms, out, NBLOCKS);
}